// Round 3
// baseline (3352.327 us; speedup 1.0000x reference)
//
#include <hip/hip_runtime.h>
#include <hip/hip_bf16.h>
#include <stdint.h>

// ContinuousActorCritic: B=256, T=2048, I=128, H=256, A=8
#define BB 256
#define TT 2048
#define II 128
#define HH 256

typedef float  float2_t  __attribute__((ext_vector_type(2)));
typedef float  float4_t  __attribute__((ext_vector_type(4)));
typedef unsigned short ushort4_t __attribute__((ext_vector_type(4)));

__device__ __forceinline__ float bf2f(unsigned short u) {
    union { unsigned int i; float f; } v;
    v.i = ((unsigned int)u) << 16;
    return v.f;
}

// One block per batch row; 512 threads = 8 waves (2/SIMD, 1 block/CU).
// Thread (j = tid>>1, kh = tid&1): output j, K-half kh of the fused K=384 row
// [W_hh row j | W_ih row j]. All math fp32. Input/output storage dtype
// (fp32 vs bf16) detected at runtime from W_hh bit patterns (wave-uniform,
// deterministic). One __syncthreads per step.
__global__ __launch_bounds__(512, 2)
void rnn_actor_critic(const void* __restrict__ xv,
                      const void* __restrict__ hxv,
                      const void* __restrict__ Wihv,
                      const void* __restrict__ Whhv,
                      const void* __restrict__ Wactv,
                      const void* __restrict__ Wcritv,
                      void* __restrict__ outv)
{
    const int b   = blockIdx.x;
    const int tid = threadIdx.x;
    const int j   = tid >> 1;   // 0..255
    const int kh  = tid & 1;    // K-half
    const int k0  = kh * 192;

    __shared__ __align__(16) float s_h[2][HH];        // h double buffer (fp32)
    __shared__ __align__(16) float s_x[2][16 * II];   // x chunk ring (fp32)
    __shared__ int s_flag;

    // ---- runtime storage-dtype detection (uniform across all blocks) ----
    // bf16 W_hh ~ N(0,0.094): every ushort exponent field <= ~125.
    // fp32 storage read as ushorts: ~half are low-mantissa words with
    // uniform exponent fields -> many > 128.
    if (tid == 0) {
        const unsigned short* p = (const unsigned short*)Whhv;
        int cnt = 0;
        for (int i = 0; i < 256; ++i) {
            int e = (p[i] >> 7) & 0xFF;
            cnt += (e > 128) ? 1 : 0;
        }
        s_flag = (cnt > 16) ? 1 : 0;   // 1 => fp32 storage
    }
    __syncthreads();
    const bool f32io = (s_flag != 0);

    // ---- preload this thread's 192 fused-row weights as fp32 ----
    // wv[0..31]  -> k = k0..k0+63   (loop 1), wv[32..95] -> k = k0+64..k0+191 (loop 2)
    float2_t wv[96];
    if (f32io) {
        const float* Whh = (const float*)Whhv;
        const float* Wih = (const float*)Wihv;
#pragma unroll
        for (int q = 0; q < 48; ++q) {
            const int k = k0 + 4 * q;
            const float* src = (k < HH) ? (Whh + j * HH + k)
                                        : (Wih + j * II + (k - HH));
            float4_t u = *(const float4_t*)src;
            float2_t a, c;
            a.x = u.x; a.y = u.y; c.x = u.z; c.y = u.w;
            wv[2 * q] = a; wv[2 * q + 1] = c;
        }
    } else {
        const unsigned short* Whh = (const unsigned short*)Whhv;
        const unsigned short* Wih = (const unsigned short*)Wihv;
#pragma unroll
        for (int q = 0; q < 48; ++q) {
            const int k = k0 + 4 * q;
            const unsigned short* src = (k < HH) ? (Whh + j * HH + k)
                                                 : (Wih + j * II + (k - HH));
            ushort4_t u = *(const ushort4_t*)src;
            float2_t a, c;
            a.x = bf2f(u.x); a.y = bf2f(u.y);
            c.x = bf2f(u.z); c.y = bf2f(u.w);
            wv[2 * q] = a; wv[2 * q + 1] = c;
        }
    }

    // ---- init h state ----
    float hreg;
    if (f32io) {
        const float* hx = (const float*)hxv;
        hreg = hx[b * HH + j];
        if (tid < HH) s_h[0][tid] = hx[b * HH + tid];
    } else {
        const unsigned short* hx = (const unsigned short*)hxv;
        hreg = bf2f(hx[b * HH + j]);
        if (tid < HH) s_h[0][tid] = bf2f(hx[b * HH + tid]);
    }

    // ---- preload x chunk 0 (steps 0..15): 2048 values, 4 per thread ----
    if (f32io) {
        const float4_t* gp = (const float4_t*)((const float*)xv + (size_t)b * TT * II);
        *(float4_t*)&s_x[0][4 * tid] = gp[tid];
    } else {
        const ushort4_t* gp = (const ushort4_t*)((const unsigned short*)xv + (size_t)b * TT * II);
        ushort4_t u = gp[tid];
        float4_t f;
        f.x = bf2f(u.x); f.y = bf2f(u.y); f.z = bf2f(u.z); f.w = bf2f(u.w);
        *(float4_t*)&s_x[0][4 * tid] = f;
    }
    __syncthreads();

    float4_t  xpf;   // fp32-path prefetch register
    ushort4_t xpu;   // bf16-path prefetch register
    for (int t = 0; t < TT; ++t) {
        const int par   = t & 1;
        const int slot  = (t >> 4) & 1;
        const int slice = t & 15;

        // prefetch next x chunk into registers (latency amortized over 16 steps)
        if (slice == 0 && t + 16 < TT) {
            if (f32io) {
                const float4_t* gp =
                    (const float4_t*)((const float*)xv + ((size_t)b * TT + (t + 16)) * II);
                xpf = gp[tid];
            } else {
                const ushort4_t* gp =
                    (const ushort4_t*)((const unsigned short*)xv + ((size_t)b * TT + (t + 16)) * II);
                xpu = gp[tid];
            }
        }

        // branch-free operand bases (kh diverges within the wave; reads are
        // 2-distinct-address wave broadcasts -> conflict-free per m136):
        //   loop1 (64 els):  kh=0 -> h[0..63],   kh=1 -> h[192..255]
        //   loop2 (128 els): kh=0 -> h[64..191], kh=1 -> x_t[0..127]
        const float* base1 = s_h[par] + kh * 192;
        const float* base2 = kh ? &s_x[slot][slice * II] : &s_h[par][64];

        float2_t acc2 = {0.f, 0.f};
#pragma unroll
        for (int q = 0; q < 16; ++q) {
            float4_t v = *(const float4_t*)(base1 + 4 * q);
            float2_t v01, v23;
            v01.x = v.x; v01.y = v.y; v23.x = v.z; v23.y = v.w;
            acc2 += wv[2 * q] * v01 + wv[2 * q + 1] * v23;
        }
#pragma unroll
        for (int q = 0; q < 32; ++q) {
            float4_t v = *(const float4_t*)(base2 + 4 * q);
            float2_t v01, v23;
            v01.x = v.x; v01.y = v.y; v23.x = v.z; v23.y = v.w;
            acc2 += wv[32 + 2 * q] * v01 + wv[33 + 2 * q] * v23;
        }

        float pre = acc2.x + acc2.y;
        pre += __shfl_xor(pre, 1, 64);   // combine K-halves (partner lane)

        hreg = 0.8f * hreg + 0.2f * fmaxf(pre, 0.f);
        if (kh == 0) s_h[par ^ 1][j] = hreg;   // publish for next step

        // stage the prefetched chunk into the other ring slot
        if (slice == 15 && t + 1 < TT) {
            if (f32io) {
                *(float4_t*)&s_x[slot ^ 1][4 * tid] = xpf;
            } else {
                float4_t f;
                f.x = bf2f(xpu.x); f.y = bf2f(xpu.y);
                f.z = bf2f(xpu.z); f.w = bf2f(xpu.w);
                *(float4_t*)&s_x[slot ^ 1][4 * tid] = f;
            }
        }
        __syncthreads();
    }

    // ---- epilogue ----
    // Final h is in s_h[0] (t=2047: par=1 -> published to s_h[0]); loop ended
    // with __syncthreads so it is visible.

    // new_hx: out[2304 + b*256 + j]
    if (kh == 0) {
        if (f32io) ((float*)outv)[2304 + b * HH + j] = hreg;
        else ((__hip_bfloat16*)outv)[2304 + b * HH + j] = __float2bfloat16(hreg);
    }

    // actor_logits out[b*8 + a] (a<8), critic out[2048 + b]
    if (tid < 9) {
        float acc = 0.f;
        if (f32io) {
            const float* wr = (tid < 8) ? ((const float*)Wactv + tid * HH)
                                        : (const float*)Wcritv;
            for (int i = 0; i < HH; ++i) acc += wr[i] * s_h[0][i];
        } else {
            const unsigned short* wr = (tid < 8) ? ((const unsigned short*)Wactv + tid * HH)
                                                 : (const unsigned short*)Wcritv;
            for (int i = 0; i < HH; ++i) acc += bf2f(wr[i]) * s_h[0][i];
        }
        const int idx = (tid < 8) ? (b * 8 + tid) : (2048 + b);
        if (f32io) ((float*)outv)[idx] = acc;
        else ((__hip_bfloat16*)outv)[idx] = __float2bfloat16(acc);
    }
}

extern "C" void kernel_launch(void* const* d_in, const int* in_sizes, int n_in,
                              void* d_out, int out_size, void* d_ws, size_t ws_size,
                              hipStream_t stream) {
    // dict order: x [256,2048,128], hx [1,256,256], W_ih [256,128],
    //             W_hh [256,256], W_actor [8,256], W_critic [1,256]
    rnn_actor_critic<<<dim3(BB), dim3(512), 0, stream>>>(
        d_in[0], d_in[1], d_in[2], d_in[3], d_in[4], d_in[5], d_out);
}

// Round 5
// 2194.759 us; speedup vs baseline: 1.5274x; 1.5274x over previous
//
#include <hip/hip_runtime.h>
#include <hip/hip_bf16.h>
#include <stdint.h>

// ContinuousActorCritic: B=256, T=2048, I=128, H=256, A=8
#define BB 256
#define TT 2048
#define II 128
#define HH 256

typedef _Float16       f16x8    __attribute__((ext_vector_type(8)));  // 4 VGPR
typedef float          f32x4    __attribute__((ext_vector_type(4)));
typedef unsigned short ushort8_t __attribute__((ext_vector_type(8)));
typedef float          float4_t __attribute__((ext_vector_type(4)));

__device__ __forceinline__ float bf2f(unsigned short u) {
    union { unsigned int i; float f; } v; v.i = ((unsigned int)u) << 16; return v.f;
}

// One block per batch row; 256 threads = 4 waves, 1 wave/SIMD (512-VGPR budget:
// 48 B-frags = 192 VGPR stay resident).
// Wave w owns outputs [w*64, w*64+64) as 4 MFMA N-tiles over fused K=384
// ([W_hh | W_ih], bf16->f16 EXACT). h state is fp32 in regs; its MFMA operand
// is hi/lo-split f16 (h_hi + h_lo/2048, 22-bit mantissa ~ fp32) because the
// recurrence is marginally chaotic and amplifies per-step operand rounding
// ~1e3-1e4x over 2048 steps (R3 fp32: 3.9e-3; R4 bf16 operand: 1.17 FAIL).
// A-operand = v broadcast across all 16 M rows; lane l extracts output
// w*64+l from acc[tile=quad][reg 0]. One __syncthreads per step.
__global__ __launch_bounds__(256, 1)
void rnn_mfma_hilo(const void* __restrict__ xv,  const void* __restrict__ hxv,
                   const void* __restrict__ Wihv, const void* __restrict__ Whhv,
                   const void* __restrict__ Wactv, const void* __restrict__ Wcritv,
                   void* __restrict__ outv)
{
    const int b    = blockIdx.x;
    const int tid  = threadIdx.x;
    const int w    = tid >> 6;
    const int l    = tid & 63;
    const int quad = l >> 4;
    const int col  = l & 15;
    const int jown = w * 64 + l;          // == tid

    __shared__ __align__(16) _Float16 s_hhi[2][HH];      // h_hi operand, dbuf
    __shared__ __align__(16) _Float16 s_hlo[2][HH];      // h_lo*2048 operand, dbuf
    __shared__ __align__(16) _Float16 s_x[2][16 * II];   // x chunk ring (f16, exact)
    __shared__ float s_hf[HH];                           // final h fp32 (heads)
    __shared__ int s_flag;

    // ---- storage-dtype detector (R3-proven; bf16 expected) ----
    if (tid == 0) {
        const unsigned short* p = (const unsigned short*)Whhv;
        int cnt = 0;
        for (int i = 0; i < 256; ++i) { int e = (p[i] >> 7) & 0xFF; cnt += (e > 128) ? 1 : 0; }
        s_flag = (cnt > 16) ? 1 : 0;   // 1 => fp32 storage
    }
    __syncthreads();
    const bool f32io = (s_flag != 0);

    // ---- B-fragments, register-stationary, f16 (bf16->f16 exact) ----
    // bfrag[c*4+t]: lane holds W(j, k0..k0+7) as f16, j = w*64 + t*16 + col,
    // k0 = 32c + quad*8.  c 0..7: W_hh (k<256); c 8..11: W_ih (k-256).
    f16x8 bfrag[48];
#pragma unroll
    for (int c = 0; c < 12; ++c) {
#pragma unroll
        for (int t = 0; t < 4; ++t) {
            const int j  = w * 64 + t * 16 + col;
            const int k0 = 32 * c + quad * 8;
            f16x8 bv;
            if (!f32io) {
                const unsigned short* src = (k0 < HH)
                    ? ((const unsigned short*)Whhv + j * HH + k0)
                    : ((const unsigned short*)Wihv + j * II + (k0 - HH));
                ushort8_t u = *(const ushort8_t*)src;
#pragma unroll
                for (int e = 0; e < 8; ++e) bv[e] = (_Float16)bf2f(u[e]);
            } else {
                const float* src = (k0 < HH)
                    ? ((const float*)Whhv + j * HH + k0)
                    : ((const float*)Wihv + j * II + (k0 - HH));
#pragma unroll
                for (int e = 0; e < 8; ++e) bv[e] = (_Float16)src[e];
            }
            bfrag[c * 4 + t] = bv;
        }
    }

    // ---- init h (fp32 state; publish hi/lo operand) ----
    float hreg;
    {
        float hv;
        if (!f32io) {
            const unsigned short* hx = (const unsigned short*)hxv;
            hreg = bf2f(hx[b * HH + jown]);
            hv   = hreg;
        } else {
            const float* hx = (const float*)hxv;
            hreg = hx[b * HH + jown];
            hv   = hreg;
        }
        _Float16 hi = (_Float16)hv;
        _Float16 lo = (_Float16)((hv - (float)hi) * 2048.f);
        s_hhi[0][jown] = hi;
        s_hlo[0][jown] = lo;
    }

    // ---- preload x chunk 0 (16 steps x 128 = 2048 els; 8/thread) as f16 ----
    if (!f32io) {
        const ushort8_t* gp = (const ushort8_t*)((const unsigned short*)xv + (size_t)b * TT * II);
        ushort8_t u = gp[tid];
        f16x8 f;
#pragma unroll
        for (int e = 0; e < 8; ++e) f[e] = (_Float16)bf2f(u[e]);
        *(f16x8*)&s_x[0][tid * 8] = f;
    } else {
        const float* gp = (const float*)xv + (size_t)b * TT * II + tid * 8;
        f16x8 f;
#pragma unroll
        for (int e = 0; e < 8; ++e) f[e] = (_Float16)gp[e];
        *(f16x8*)&s_x[0][tid * 8] = f;
    }
    __syncthreads();

    ushort8_t xpu;     // bf16-path prefetch
    float4_t  xpf[2];  // fp32-path prefetch
    for (int t = 0; t < TT; ++t) {
        const int par   = t & 1;
        const int slot  = (t >> 4) & 1;
        const int slice = t & 15;

        // prefetch next 16-step x chunk (HBM latency amortized over 15 steps)
        if (slice == 0 && t + 16 < TT) {
            if (!f32io) {
                const ushort8_t* gp = (const ushort8_t*)((const unsigned short*)xv
                                        + ((size_t)b * TT + (t + 16)) * II);
                xpu = gp[tid];
            } else {
                const float4_t* gp = (const float4_t*)((const float*)xv
                                        + ((size_t)b * TT + (t + 16)) * II) + tid * 2;
                xpf[0] = gp[0]; xpf[1] = gp[1];
            }
        }

        const _Float16* hbh = s_hhi[par];
        const _Float16* hbl = s_hlo[par];
        const _Float16* xb  = &s_x[slot][slice * II];

        f32x4 acch[4], accl[4];
#pragma unroll
        for (int tt = 0; tt < 4; ++tt) {
            acch[tt] = (f32x4){0.f, 0.f, 0.f, 0.f};
            accl[tt] = (f32x4){0.f, 0.f, 0.f, 0.f};
        }

#pragma unroll
        for (int c = 0; c < 8; ++c) {           // h_hi part: k = 32c + quad*8
            f16x8 a = *(const f16x8*)(hbh + 32 * c + quad * 8);
#pragma unroll
            for (int tt = 0; tt < 4; ++tt)
                acch[tt] = __builtin_amdgcn_mfma_f32_16x16x32_f16(a, bfrag[c * 4 + tt], acch[tt], 0, 0, 0);
        }
#pragma unroll
        for (int c = 0; c < 8; ++c) {           // h_lo part (same weights)
            f16x8 a = *(const f16x8*)(hbl + 32 * c + quad * 8);
#pragma unroll
            for (int tt = 0; tt < 4; ++tt)
                accl[tt] = __builtin_amdgcn_mfma_f32_16x16x32_f16(a, bfrag[c * 4 + tt], accl[tt], 0, 0, 0);
        }
#pragma unroll
        for (int c = 0; c < 4; ++c) {           // x part: k = 256 + 32c + quad*8
            f16x8 a = *(const f16x8*)(xb + 32 * c + quad * 8);
#pragma unroll
            for (int tt = 0; tt < 4; ++tt)
                acch[tt] = __builtin_amdgcn_mfma_f32_16x16x32_f16(a, bfrag[32 + c * 4 + tt], acch[tt], 0, 0, 0);
        }

        // all 16 D-rows identical; lane l takes tile=quad, col, reg 0
        float ph = (quad & 2) ? ((quad & 1) ? acch[3][0] : acch[2][0])
                              : ((quad & 1) ? acch[1][0] : acch[0][0]);
        float pl = (quad & 2) ? ((quad & 1) ? accl[3][0] : accl[2][0])
                              : ((quad & 1) ? accl[1][0] : accl[0][0]);
        float pre = ph + pl * (1.f / 2048.f);

        hreg = 0.8f * hreg + 0.2f * fmaxf(pre, 0.f);

        _Float16 hi = (_Float16)hreg;
        _Float16 lo = (_Float16)((hreg - (float)hi) * 2048.f);
        s_hhi[par ^ 1][jown] = hi;
        s_hlo[par ^ 1][jown] = lo;

        // stage prefetched x chunk into the other ring slot
        if (slice == 15) {
            if (t + 1 < TT) {
                f16x8 f;
                if (!f32io) {
#pragma unroll
                    for (int e = 0; e < 8; ++e) f[e] = (_Float16)bf2f(xpu[e]);
                } else {
#pragma unroll
                    for (int e = 0; e < 4; ++e) { f[e] = (_Float16)xpf[0][e]; f[4 + e] = (_Float16)xpf[1][e]; }
                }
                *(f16x8*)&s_x[slot ^ 1][tid * 8] = f;
            } else {
                s_hf[jown] = hreg;              // t == TT-1: publish fp32 h for heads
            }
        }
        __syncthreads();
    }

    // ---- epilogue ----
    // new_hx: out[2304 + b*256 + j] (fp32 state)
    if (!f32io) ((__hip_bfloat16*)outv)[2304 + b * HH + jown] = __float2bfloat16(hreg);
    else        ((float*)outv)[2304 + b * HH + jown] = hreg;

    // actor_logits out[b*8 + a], critic out[2048 + b]
    if (tid < 9) {
        float acc = 0.f;
        if (!f32io) {
            const unsigned short* wr = (tid < 8) ? ((const unsigned short*)Wactv + tid * HH)
                                                 : (const unsigned short*)Wcritv;
            for (int i = 0; i < HH; ++i) acc += bf2f(wr[i]) * s_hf[i];
        } else {
            const float* wr = (tid < 8) ? ((const float*)Wactv + tid * HH)
                                        : (const float*)Wcritv;
            for (int i = 0; i < HH; ++i) acc += wr[i] * s_hf[i];
        }
        const int idx = (tid < 8) ? (b * 8 + tid) : (2048 + b);
        if (!f32io) ((__hip_bfloat16*)outv)[idx] = __float2bfloat16(acc);
        else        ((float*)outv)[idx] = acc;
    }
}

extern "C" void kernel_launch(void* const* d_in, const int* in_sizes, int n_in,
                              void* d_out, int out_size, void* d_ws, size_t ws_size,
                              hipStream_t stream) {
    // dict order: x [256,2048,128], hx [1,256,256], W_ih [256,128],
    //             W_hh [256,256], W_actor [8,256], W_critic [1,256]
    rnn_mfma_hilo<<<dim3(BB), dim3(256), 0, stream>>>(
        d_in[0], d_in[1], d_in[2], d_in[3], d_in[4], d_in[5], d_out);
}